// Round 12
// baseline (58008.203 us; speedup 1.0000x reference)
//
#include <hip/hip_runtime.h>
#include <hip/hip_bf16.h>
#include <hip/hip_fp16.h>

#define B_ 64
#define T_ 1024
#define D_ 512
#define H_ 512
#define O_ 512
#define NBLK 32   // fallback-path step-kernel blocks

using bf16x8 = __attribute__((ext_vector_type(8))) short;
using f32x4  = __attribute__((ext_vector_type(4))) float;

__device__ __forceinline__ short f2bfs(float f) {
  return (short)__builtin_bit_cast(unsigned short, __float2bfloat16(f));
}
__device__ __forceinline__ float sigmoid_f(float v) {
  return 1.0f / (1.0f + __expf(-v));
}
__device__ __forceinline__ float tanh_f(float v) {
  float a = fabsf(v);
  float e = __expf(-2.0f * a);
  float t = (1.0f - e) / (1.0f + e);
  return copysignf(t, v);
}
__device__ __forceinline__ unsigned short f2h(float f) {
  return __half_as_ushort(__float2half_rn(f));
}
__device__ __forceinline__ float h2f(unsigned short u) {
  __half_raw r; r.x = u; return __half2float(__half(r));
}

// ---------------------------------------------------------------------------
// Setup: pack W_all (1024x2048) and W_hy (512x512) into MFMA B-fragment order
// (bf16); stage h_init (bf16) + c_init (fp32) for the fallback path.
// ---------------------------------------------------------------------------
__global__ __launch_bounds__(256) void pack_setup(
    const float* __restrict__ Wf, const float* __restrict__ Wi,
    const float* __restrict__ Wc, const float* __restrict__ Wo,
    const float* __restrict__ Why, const float* __restrict__ hinit,
    const float* __restrict__ cinit,
    unsigned short* __restrict__ Wp, unsigned short* __restrict__ Whyp,
    unsigned short* __restrict__ hbf0, float* __restrict__ cbuf)
{
  long idx = (long)blockIdx.x * blockDim.x + threadIdx.x;
  const long NW = 1024L * 2048;
  const long NY = 512L * 512;
  const long NH = 64L * 512;
  const long NC = 64L * 512;
  if (idx < NW) {
    int e = idx & 7, l = (idx >> 3) & 63, kk = (idx >> 9) & 31;
    int Jc = (int)(idx >> 14);                   // 0..127
    int k = kk * 32 + (l >> 4) * 8 + e;          // 0..1023
    int col = Jc * 16 + (l & 15);                // 0..2047
    int gg = col >> 9, j = col & 511;
    const float* W = (gg == 0) ? Wf : (gg == 1) ? Wi : (gg == 2) ? Wc : Wo;
    Wp[idx] = (unsigned short)f2bfs(W[(long)k * 512 + j]);
  } else if (idx < NW + NY) {
    long q = idx - NW;
    int e = q & 7, l = (q >> 3) & 63, kk = (q >> 9) & 15;
    int J = (int)(q >> 13);
    int k = kk * 32 + (l >> 4) * 8 + e;
    int col = J * 16 + (l & 15);
    Whyp[q] = (unsigned short)f2bfs(Why[(long)k * 512 + col]);
  } else if (idx < NW + NY + NH) {
    long q = idx - NW - NY;
    hbf0[q] = (unsigned short)f2bfs(hinit[q]);
  } else if (idx < NW + NY + NH + NC) {
    long q = idx - NW - NY - NH;
    cbuf[q] = cinit[q];
  }
}

// ---------------------------------------------------------------------------
// NEW PATH 1/2: ZX precompute.
// ZXp[mt][Jc][lane][4] fp16 = bias + X @ W_x, stored in MFMA C-fragment
// layout so the recurrent kernel's acc-init is one coalesced dwordx2/tile.
// m = t*64 + b (t-major);  m-tile mt = 4t + g covers batch group g at step t.
// Grid: 2048 blocks x 512 threads; block handles m-tiles {2bk, 2bk+1}.
// ---------------------------------------------------------------------------
__global__ __launch_bounds__(512) void zx_pre(
    const float* __restrict__ x,
    const float* __restrict__ bf_, const float* __restrict__ bi_,
    const float* __restrict__ bc_, const float* __restrict__ bo_,
    const unsigned short* __restrict__ Wp,
    unsigned int* __restrict__ zxp)
{
  const int tid  = threadIdx.x;
  const int wv   = tid >> 6;
  const int lane = tid & 63;
  const int lrow = lane & 15;
  const int lkg  = lane >> 4;
  const long mt  = (long)blockIdx.x * 2 + (wv & 1);   // 0..4095
  const int  ng  = wv >> 1;                           // 0..3
  const int  t   = (int)(mt >> 2);
  const int  b   = ((int)mt & 3) * 16 + lrow;

  // A-frags: lane reads x[b][t][k], k = kk*32 + lkg*8 + e  (fp32 -> bf16)
  const float* xp = x + ((long)b * T_ + t) * D_ + lkg * 8;
  bf16x8 af[16];
  #pragma unroll
  for (int kk = 0; kk < 16; ++kk) {
    float4 a  = *(const float4*)(xp + kk * 32);
    float4 b4 = *(const float4*)(xp + kk * 32 + 4);
    bf16x8 v;
    v[0]=f2bfs(a.x); v[1]=f2bfs(a.y); v[2]=f2bfs(a.z); v[3]=f2bfs(a.w);
    v[4]=f2bfs(b4.x); v[5]=f2bfs(b4.y); v[6]=f2bfs(b4.z); v[7]=f2bfs(b4.w);
    af[kk] = v;
  }

  f32x4 acc[32];
  #pragma unroll
  for (int nt = 0; nt < 32; ++nt) {
    int col = (ng * 32 + nt) * 16 + lrow;
    const float* bp = col < 512 ? bf_ : col < 1024 ? bi_ : col < 1536 ? bc_ : bo_;
    float bb = bp[col & 511];
    acc[nt] = {bb, bb, bb, bb};
  }

  #pragma unroll
  for (int kk = 0; kk < 16; ++kk) {
    #pragma unroll
    for (int nt = 0; nt < 32; ++nt) {
      int Jc = ng * 32 + nt;
      bf16x8 wf = *(const bf16x8*)(Wp + ((long)(Jc * 32 + kk + 16) * 64 + lane) * 8);
      acc[nt] = __builtin_amdgcn_mfma_f32_16x16x32_bf16(af[kk], wf, acc[nt], 0, 0, 0);
    }
  }

  #pragma unroll
  for (int nt = 0; nt < 32; ++nt) {
    int Jc = ng * 32 + nt;
    unsigned u0 = (unsigned)f2h(acc[nt][0]) | ((unsigned)f2h(acc[nt][1]) << 16);
    unsigned u1 = (unsigned)f2h(acc[nt][2]) | ((unsigned)f2h(acc[nt][3]) << 16);
    uint2 uu; uu.x = u0; uu.y = u1;
    *(uint2*)(zxp + ((mt * 128 + Jc) * 64 + lane) * 2) = uu;
  }
}

// ---------------------------------------------------------------------------
// NEW PATH 2/2: sync-free recurrence. 4 blocks x 512 threads (8 waves).
// Block g owns batch rows [16g,16g+16) END-TO-END: h lives in LDS (dbuf),
// c in registers, gates entirely in accumulator registers (wave w owns the
// matching f/i/g/o column tiles for h-cols [64w,64w+64)). Per step: acc-init
// from prefetched ZX, 16 ds_reads (h A-frags), 256 MFMAs + 256 W-loads per
// wave (W streams from per-XCD L2, read-only), gates, ONE __syncthreads.
// NO inter-block communication anywhere.
// ---------------------------------------------------------------------------
__global__ __launch_bounds__(512) void lstm_rec(
    const float* __restrict__ hinit, const float* __restrict__ cinit,
    const unsigned short* __restrict__ Wp,
    const unsigned int* __restrict__ zxp,
    unsigned short* __restrict__ hs,   // (T,B,H) bf16
    float* __restrict__ tail)          // h_fin then c_fin
{
  __shared__ unsigned short hlds[2][16][520];   // +8 pad: conflict-free reads

  const int g    = blockIdx.x;       // 0..3 batch group
  const int tid  = threadIdx.x;
  const int wv   = tid >> 6;         // 0..7
  const int lane = tid & 63;
  const int lrow = lane & 15;
  const int lkg  = lane >> 4;

  // init h LDS (bf16) from h_init
  for (int q = tid; q < 16 * 512; q += 512) {
    int r = q >> 9, cL = q & 511;
    hlds[0][r][cL] = (unsigned short)f2bfs(hinit[(long)(16 * g + r) * 512 + cL]);
  }
  // c state: cst[tt*4+i2] for rows lkg*4+i2, cols wv*64+tt*16+lrow
  float cst[16];
  #pragma unroll
  for (int tt = 0; tt < 4; ++tt)
    #pragma unroll
    for (int i2 = 0; i2 < 4; ++i2)
      cst[tt * 4 + i2] =
          cinit[(long)(16 * g + lkg * 4 + i2) * 512 + wv * 64 + tt * 16 + lrow];
  __syncthreads();

  // zx prefetch for t=0: tile j -> Jc = (j>>2)*32 + wv*4 + (j&3)
  uint2 zx[16];
  #pragma unroll
  for (int j = 0; j < 16; ++j) {
    int Jc = (j >> 2) * 32 + wv * 4 + (j & 3);
    zx[j] = *(const uint2*)(zxp + (((long)g * 128 + Jc) * 64 + lane) * 2);
  }

  #pragma unroll 1
  for (int t = 0; t < T_; ++t) {
    // acc init = zx (bias + x@Wx, fp16 -> fp32)
    f32x4 acc[16];
    #pragma unroll
    for (int j = 0; j < 16; ++j) {
      acc[j][0] = h2f((unsigned short)(zx[j].x & 0xffffu));
      acc[j][1] = h2f((unsigned short)(zx[j].x >> 16));
      acc[j][2] = h2f((unsigned short)(zx[j].y & 0xffffu));
      acc[j][3] = h2f((unsigned short)(zx[j].y >> 16));
    }
    // prefetch zx for t+1 (latency hidden under the MFMA phase)
    {
      const long tn = (t + 1 < T_) ? (long)(t + 1) : (long)t;
      const long mtn = 4 * tn + g;
      #pragma unroll
      for (int j = 0; j < 16; ++j) {
        int Jc = (j >> 2) * 32 + wv * 4 + (j & 3);
        zx[j] = *(const uint2*)(zxp + ((mtn * 128 + Jc) * 64 + lane) * 2);
      }
    }
    // h A-frags from LDS (conflict-free: row stride 1040 B)
    const int pb = t & 1;
    bf16x8 hf[16];
    #pragma unroll
    for (int kk = 0; kk < 16; ++kk)
      hf[kk] = *(const bf16x8*)(&hlds[pb][lrow][kk * 32 + lkg * 8]);

    // MFMA: 16 tiles x K=512 (16 k-slices); W streamed from L2 (coalesced 1KB)
    #pragma unroll
    for (int j = 0; j < 16; ++j) {
      int Jc = (j >> 2) * 32 + wv * 4 + (j & 3);
      const unsigned short* wb = Wp + ((long)Jc * 32 * 64 + lane) * 8;
      #pragma unroll
      for (int kk = 0; kk < 16; ++kk) {
        bf16x8 wf = *(const bf16x8*)(wb + (long)kk * 512);
        acc[j] = __builtin_amdgcn_mfma_f32_16x16x32_bf16(hf[kk], wf, acc[j], 0, 0, 0);
      }
    }

    // gates in registers: f=acc[tt], i=acc[4+tt], g=acc[8+tt], o=acc[12+tt]
    #pragma unroll
    for (int tt = 0; tt < 4; ++tt) {
      #pragma unroll
      for (int i2 = 0; i2 < 4; ++i2) {
        float fg = sigmoid_f(acc[tt][i2]);
        float ig = sigmoid_f(acc[4 + tt][i2]);
        float gg = tanh_f(acc[8 + tt][i2]);
        float og = sigmoid_f(acc[12 + tt][i2]);
        float c = fg * cst[tt * 4 + i2] + ig * gg;
        cst[tt * 4 + i2] = c;
        float hv = og * tanh_f(c);
        unsigned short hb = (unsigned short)f2bfs(hv);
        int row = lkg * 4 + i2;
        int col = wv * 64 + tt * 16 + lrow;
        hlds[pb ^ 1][row][col] = hb;
        __builtin_nontemporal_store(
            hb, hs + ((long)t * 64 + 16 * g + row) * 512 + col);
        if (t == T_ - 1) {
          tail[(long)(16 * g + row) * 512 + col] = hv;
          tail[64L * 512 + (long)(16 * g + row) * 512 + col] = c;
        }
      }
    }
    __syncthreads();   // the ONLY per-step barrier (intra-CU, ~100 cyc)
  }
}

// ---------------------------------------------------------------------------
// FALLBACK (proven R10): x -> bf16 conversion + one kernel per timestep.
// ---------------------------------------------------------------------------
__global__ __launch_bounds__(256) void xconv(
    const float* __restrict__ x, unsigned short* __restrict__ xb)
{
  long i = ((long)blockIdx.x * 256 + threadIdx.x) * 8;
  float4 a = *(const float4*)(x + i);
  float4 b = *(const float4*)(x + i + 4);
  bf16x8 v;
  v[0] = f2bfs(a.x); v[1] = f2bfs(a.y); v[2] = f2bfs(a.z); v[3] = f2bfs(a.w);
  v[4] = f2bfs(b.x); v[5] = f2bfs(b.y); v[6] = f2bfs(b.z); v[7] = f2bfs(b.w);
  *(bf16x8*)(xb + i) = v;
}

template<bool X16>
__global__ __launch_bounds__(256) void lstm_step(
    const void* __restrict__ xv,
    const float* __restrict__ bf_, const float* __restrict__ bi_,
    const float* __restrict__ bc_, const float* __restrict__ bo_,
    const unsigned short* __restrict__ Wp,
    const unsigned short* __restrict__ hin,
    unsigned short* __restrict__ hout,
    float* __restrict__ cbuf,
    unsigned short* __restrict__ hs,
    float* __restrict__ tail,
    int t)
{
  const int jb   = blockIdx.x;
  const int tid  = threadIdx.x;
  const int wv   = tid >> 6;
  const int lane = tid & 63;
  const int lrow = lane & 15;
  const int lkg  = lane >> 4;
  const int b_arow = wv * 16 + lrow;
  const int jcol   = jb * 16 + lrow;
  const int b_cd0  = wv * 16 + lkg * 4;

  const unsigned short* hrow = hin + (long)b_arow * H_ + lkg * 8;
  bf16x8 hf[16];
  #pragma unroll
  for (int kk = 0; kk < 16; ++kk) hf[kk] = *(const bf16x8*)(hrow + kk * 32);

  bf16x8 xf[16];
  float4 xr[32];
  if constexpr (X16) {
    const unsigned short* xt = (const unsigned short*)xv
        + (long)b_arow * T_ * D_ + (long)t * D_ + lkg * 8;
    #pragma unroll
    for (int kk = 0; kk < 16; ++kk) xf[kk] = *(const bf16x8*)(xt + kk * 32);
  } else {
    const float* xt = (const float*)xv
        + (long)b_arow * T_ * D_ + (long)t * D_ + lkg * 8;
    #pragma unroll
    for (int kk = 0; kk < 16; ++kk) {
      xr[2*kk]   = *(const float4*)(xt + kk * 32);
      xr[2*kk+1] = *(const float4*)(xt + kk * 32 + 4);
    }
  }

  const float vbf = bf_[jcol], vbi = bi_[jcol], vbc = bc_[jcol], vbo = bo_[jcol];
  float c0 = cbuf[(long)(b_cd0 + 0) * H_ + jcol];
  float c1 = cbuf[(long)(b_cd0 + 1) * H_ + jcol];
  float c2 = cbuf[(long)(b_cd0 + 2) * H_ + jcol];
  float c3 = cbuf[(long)(b_cd0 + 3) * H_ + jcol];

  const unsigned short* w0 = Wp + (long)(0 * 32 + jb) * 32 * 512 + lane * 8;
  const unsigned short* w1 = Wp + (long)(1 * 32 + jb) * 32 * 512 + lane * 8;
  const unsigned short* w2 = Wp + (long)(2 * 32 + jb) * 32 * 512 + lane * 8;
  const unsigned short* w3 = Wp + (long)(3 * 32 + jb) * 32 * 512 + lane * 8;

  f32x4 af = {vbf, vbf, vbf, vbf};
  f32x4 ai = {vbi, vbi, vbi, vbi};
  f32x4 ac = {vbc, vbc, vbc, vbc};
  f32x4 ao = {vbo, vbo, vbo, vbo};

  #pragma unroll
  for (int kk = 0; kk < 16; ++kk) {
    bf16x8 ah = hf[kk];
    af = __builtin_amdgcn_mfma_f32_16x16x32_bf16(ah, *(const bf16x8*)(w0 + kk * 512), af, 0, 0, 0);
    ai = __builtin_amdgcn_mfma_f32_16x16x32_bf16(ah, *(const bf16x8*)(w1 + kk * 512), ai, 0, 0, 0);
    ac = __builtin_amdgcn_mfma_f32_16x16x32_bf16(ah, *(const bf16x8*)(w2 + kk * 512), ac, 0, 0, 0);
    ao = __builtin_amdgcn_mfma_f32_16x16x32_bf16(ah, *(const bf16x8*)(w3 + kk * 512), ao, 0, 0, 0);
    bf16x8 ax;
    if constexpr (X16) {
      ax = xf[kk];
    } else {
      float4 xa = xr[2*kk], xb2 = xr[2*kk+1];
      ax[0]=f2bfs(xa.x); ax[1]=f2bfs(xa.y); ax[2]=f2bfs(xa.z); ax[3]=f2bfs(xa.w);
      ax[4]=f2bfs(xb2.x); ax[5]=f2bfs(xb2.y); ax[6]=f2bfs(xb2.z); ax[7]=f2bfs(xb2.w);
    }
    const int k2 = kk + 16;
    af = __builtin_amdgcn_mfma_f32_16x16x32_bf16(ax, *(const bf16x8*)(w0 + k2 * 512), af, 0, 0, 0);
    ai = __builtin_amdgcn_mfma_f32_16x16x32_bf16(ax, *(const bf16x8*)(w1 + k2 * 512), ai, 0, 0, 0);
    ac = __builtin_amdgcn_mfma_f32_16x16x32_bf16(ax, *(const bf16x8*)(w2 + k2 * 512), ac, 0, 0, 0);
    ao = __builtin_amdgcn_mfma_f32_16x16x32_bf16(ax, *(const bf16x8*)(w3 + k2 * 512), ao, 0, 0, 0);
  }

  #pragma unroll
  for (int i2 = 0; i2 < 4; ++i2) {
    float fg = sigmoid_f(af[i2]);
    float ig = sigmoid_f(ai[i2]);
    float gg = tanh_f(ac[i2]);
    float og = sigmoid_f(ao[i2]);
    float cN = (i2 == 0) ? c0 : (i2 == 1) ? c1 : (i2 == 2) ? c2 : c3;
    cN = fg * cN + ig * gg;
    float hv = og * tanh_f(cN);
    if (i2 == 0) c0 = cN; else if (i2 == 1) c1 = cN; else if (i2 == 2) c2 = cN; else c3 = cN;
    unsigned short hb = (unsigned short)f2bfs(hv);
    int brow = b_cd0 + i2;
    cbuf[(long)brow * H_ + jcol] = cN;
    hout[(long)brow * H_ + jcol] = hb;
    __builtin_nontemporal_store(hb, hs + ((long)t * B_ + brow) * H_ + jcol);
    if (t == T_ - 1) {
      tail[(long)brow * H_ + jcol] = hv;
      tail[(long)B_ * H_ + (long)brow * H_ + jcol] = cN;
    }
  }
}

// ---------------------------------------------------------------------------
// Output projection: out(B,T,O) = hs(T,B,H) @ W_hy + b_hy.  (proven)
// ---------------------------------------------------------------------------
__global__ __launch_bounds__(512) void out_proj(
    const unsigned short* __restrict__ hs,
    const unsigned short* __restrict__ Whyp,
    const float* __restrict__ bhy,
    float* __restrict__ out)
{
  const int tid  = threadIdx.x;
  const int wv   = tid >> 6;
  const int lane = tid & 63;
  const int lrow = lane & 15;
  const int lkg  = lane >> 4;
  const int mg = wv >> 2;
  const int ng = wv & 3;
  const long mbase = (long)blockIdx.x * 128 + mg * 64;

  f32x4 acc[4][8];
  #pragma unroll
  for (int mt = 0; mt < 4; ++mt)
    #pragma unroll
    for (int nt = 0; nt < 8; ++nt) {
      float b = bhy[ng * 128 + nt * 16 + lrow];
      acc[mt][nt] = {b, b, b, b};
    }

  const unsigned short* arow = hs + (mbase + lrow) * 512 + lkg * 8;
  const unsigned short* bbas = Whyp + (long)(ng * 8) * 8192 + lane * 8;

  #pragma unroll
  for (int kk = 0; kk < 16; ++kk) {
    bf16x8 a0 = *(const bf16x8*)(arow + 0 * 8192 + kk * 32);
    bf16x8 a1 = *(const bf16x8*)(arow + 1 * 8192 + kk * 32);
    bf16x8 a2 = *(const bf16x8*)(arow + 2 * 8192 + kk * 32);
    bf16x8 a3 = *(const bf16x8*)(arow + 3 * 8192 + kk * 32);
    #pragma unroll
    for (int nt = 0; nt < 8; ++nt) {
      bf16x8 bv = *(const bf16x8*)(bbas + nt * 8192 + kk * 512);
      acc[0][nt] = __builtin_amdgcn_mfma_f32_16x16x32_bf16(a0, bv, acc[0][nt], 0, 0, 0);
      acc[1][nt] = __builtin_amdgcn_mfma_f32_16x16x32_bf16(a1, bv, acc[1][nt], 0, 0, 0);
      acc[2][nt] = __builtin_amdgcn_mfma_f32_16x16x32_bf16(a2, bv, acc[2][nt], 0, 0, 0);
      acc[3][nt] = __builtin_amdgcn_mfma_f32_16x16x32_bf16(a3, bv, acc[3][nt], 0, 0, 0);
    }
  }

  #pragma unroll
  for (int mt = 0; mt < 4; ++mt) {
    #pragma unroll
    for (int i2 = 0; i2 < 4; ++i2) {
      long m = mbase + mt * 16 + lkg * 4 + i2;
      long t = m >> 6, b = m & 63;
      float* orow = out + (b * 1024 + t) * 512;
      #pragma unroll
      for (int nt = 0; nt < 8; ++nt)
        orow[ng * 128 + nt * 16 + lrow] = acc[mt][nt][i2];
    }
  }
}

// ---------------------------------------------------------------------------
extern "C" void kernel_launch(void* const* d_in, const int* in_sizes, int n_in,
                              void* d_out, int out_size, void* d_ws, size_t ws_size,
                              hipStream_t stream) {
  const float* x      = (const float*)d_in[0];
  const float* h_init = (const float*)d_in[1];
  const float* c_init = (const float*)d_in[2];
  const float* W_f = (const float*)d_in[3];
  const float* b_f = (const float*)d_in[4];
  const float* W_i = (const float*)d_in[5];
  const float* b_i = (const float*)d_in[6];
  const float* W_c = (const float*)d_in[7];
  const float* b_c = (const float*)d_in[8];
  const float* W_o = (const float*)d_in[9];
  const float* b_o = (const float*)d_in[10];
  const float* W_hy = (const float*)d_in[11];
  const float* b_hy = (const float*)d_in[12];
  float* out = (float*)d_out;

  // ws layout (bytes)
  const size_t WP_OFF   = 0;                          // 4 MB
  const size_t WHYP_OFF = 4u << 20;                   // 512 KB
  const size_t HBF0_OFF = WHYP_OFF + (512u << 10);    // 64 KB (fallback)
  const size_t HBF1_OFF = HBF0_OFF + (64u << 10);     // 64 KB (fallback)
  const size_t CB_OFF   = HBF1_OFF + (64u << 10);     // 128 KB fp32 c (fallback)
  const size_t HS_OFF   = 8u << 20;                   // 64 MB hs
  const size_t HS_BYTES = (size_t)T_ * B_ * H_ * 2;
  const size_t ZX_OFF   = HS_OFF + HS_BYTES;          // new path: 256 MB fp16
  const size_t ZX_BYTES = (size_t)4096 * 128 * 512;   // 256 MiB
  const size_t XB_OFF   = ZX_OFF;                     // fallback-big: 64 MB bf16 x
  const size_t XB_BYTES = (size_t)B_ * T_ * D_ * 2;
  const size_t NEED_MIN = HS_OFF + HS_BYTES;          // 72 MB
  const size_t NEED_NEW = ZX_OFF + ZX_BYTES;          // 328 MB
  const size_t NEED_FBB = XB_OFF + XB_BYTES;          // 136 MB
  if (ws_size < NEED_MIN) return;
  const bool newpath = (ws_size >= NEED_NEW);
  const bool fb_big  = (!newpath) && (ws_size >= NEED_FBB);

  unsigned char* w = (unsigned char*)d_ws;
  unsigned short* Wp   = (unsigned short*)(w + WP_OFF);
  unsigned short* Whyp = (unsigned short*)(w + WHYP_OFF);
  unsigned short* hbf0 = (unsigned short*)(w + HBF0_OFF);
  unsigned short* hbf1 = (unsigned short*)(w + HBF1_OFF);
  float*          cbuf = (float*)(w + CB_OFF);
  unsigned short* hs   = (unsigned short*)(w + HS_OFF);
  unsigned int*   zxp  = (unsigned int*)(w + ZX_OFF);
  unsigned short* xb   = (unsigned short*)(w + XB_OFF);

  // 1) pack weights + fallback state staging
  const long total = 1024L * 2048 + 512L * 512 + 64L * 512 + 64L * 512;
  int pgrid = (int)((total + 255) / 256);
  pack_setup<<<pgrid, 256, 0, stream>>>(W_f, W_i, W_c, W_o, W_hy, h_init, c_init,
                                        Wp, Whyp, hbf0, cbuf);

  float* tail = out + (size_t)B_ * T_ * O_;

  if (newpath) {
    // 2) ZX = bias + X @ W_x, packed in MFMA C-layout (fp16)
    zx_pre<<<2048, 512, 0, stream>>>(x, b_f, b_i, b_c, b_o, Wp, zxp);
    // 3) sync-free recurrence: 4 independent blocks, h in LDS, c in regs
    lstm_rec<<<4, 512, 0, stream>>>(h_init, c_init, Wp, zxp, hs, tail);
  } else {
    // fallback: proven kernel-per-timestep chain (R10)
    if (fb_big) {
      const long nx = (long)B_ * T_ * D_;
      int xgrid = (int)(nx / (256 * 8));
      xconv<<<xgrid, 256, 0, stream>>>(x, xb);
    }
    for (int t = 0; t < T_; ++t) {
      const unsigned short* hin  = (t & 1) ? hbf1 : hbf0;
      unsigned short*       hout = (t & 1) ? hbf0 : hbf1;
      if (fb_big) {
        lstm_step<true><<<NBLK, 256, 0, stream>>>(
            xb, b_f, b_i, b_c, b_o, Wp, hin, hout, cbuf, hs, tail, t);
      } else {
        lstm_step<false><<<NBLK, 256, 0, stream>>>(
            x, b_f, b_i, b_c, b_o, Wp, hin, hout, cbuf, hs, tail, t);
      }
    }
  }

  // 4) output projection
  out_proj<<<512, 512, 0, stream>>>(hs, Whyp, b_hy, out);
}

// Round 13
// 41106.305 us; speedup vs baseline: 1.4112x; 1.4112x over previous
//
#include <hip/hip_runtime.h>
#include <hip/hip_bf16.h>
#include <hip/hip_fp16.h>

#define B_ 64
#define T_ 1024
#define D_ 512
#define H_ 512
#define O_ 512
#define NBLK 32   // fallback-path step-kernel blocks

using bf16x8 = __attribute__((ext_vector_type(8))) short;
using f32x4  = __attribute__((ext_vector_type(4))) float;
using i32x4  = __attribute__((ext_vector_type(4))) int;

__device__ __forceinline__ short f2bfs(float f) {
  return (short)__builtin_bit_cast(unsigned short, __float2bfloat16(f));
}
__device__ __forceinline__ float sigmoid_f(float v) {
  return 1.0f / (1.0f + __expf(-v));
}
__device__ __forceinline__ float tanh_f(float v) {
  float a = fabsf(v);
  float e = __expf(-2.0f * a);
  float t = (1.0f - e) / (1.0f + e);
  return copysignf(t, v);
}
__device__ __forceinline__ unsigned short f2h(float f) {
  return __half_as_ushort(__float2half_rn(f));
}
__device__ __forceinline__ float h2f(unsigned short u) {
  __half_raw r; r.x = u; return __half2float(__half(r));
}

// ---------------------------------------------------------------------------
// Setup: pack W_all (1024x2048) and W_hy (512x512) into MFMA B-fragment order
// (bf16); stage h_init (bf16) + c_init (fp32) for the fallback path.
// ---------------------------------------------------------------------------
__global__ __launch_bounds__(256) void pack_setup(
    const float* __restrict__ Wf, const float* __restrict__ Wi,
    const float* __restrict__ Wc, const float* __restrict__ Wo,
    const float* __restrict__ Why, const float* __restrict__ hinit,
    const float* __restrict__ cinit,
    unsigned short* __restrict__ Wp, unsigned short* __restrict__ Whyp,
    unsigned short* __restrict__ hbf0, float* __restrict__ cbuf)
{
  long idx = (long)blockIdx.x * blockDim.x + threadIdx.x;
  const long NW = 1024L * 2048;
  const long NY = 512L * 512;
  const long NH = 64L * 512;
  const long NC = 64L * 512;
  if (idx < NW) {
    int e = idx & 7, l = (idx >> 3) & 63, kk = (idx >> 9) & 31;
    int Jc = (int)(idx >> 14);                   // 0..127
    int k = kk * 32 + (l >> 4) * 8 + e;          // 0..1023
    int col = Jc * 16 + (l & 15);                // 0..2047
    int gg = col >> 9, j = col & 511;
    const float* W = (gg == 0) ? Wf : (gg == 1) ? Wi : (gg == 2) ? Wc : Wo;
    Wp[idx] = (unsigned short)f2bfs(W[(long)k * 512 + j]);
  } else if (idx < NW + NY) {
    long q = idx - NW;
    int e = q & 7, l = (q >> 3) & 63, kk = (q >> 9) & 15;
    int J = (int)(q >> 13);
    int k = kk * 32 + (l >> 4) * 8 + e;
    int col = J * 16 + (l & 15);
    Whyp[q] = (unsigned short)f2bfs(Why[(long)k * 512 + col]);
  } else if (idx < NW + NY + NH) {
    long q = idx - NW - NY;
    hbf0[q] = (unsigned short)f2bfs(hinit[q]);
  } else if (idx < NW + NY + NH + NC) {
    long q = idx - NW - NY - NH;
    cbuf[q] = cinit[q];
  }
}

// ---------------------------------------------------------------------------
// i8 weight quantization (h-part only, k in [0,512)): per-column scale.
// Packed layout: Wq[((Jc*8+kk)*64 + l)*16 + e] with col = Jc*16+(l&15),
// k = kk*64 + (l>>4)*16 + e  (same lane->k map as the A-frag build).
// 2048 blocks x 64 threads (one wave per column).
// ---------------------------------------------------------------------------
__global__ __launch_bounds__(64) void wquant(
    const float* __restrict__ Wf, const float* __restrict__ Wi,
    const float* __restrict__ Wc, const float* __restrict__ Wo,
    signed char* __restrict__ Wq, float* __restrict__ sW)
{
  const int col = blockIdx.x;          // 0..2047
  const int gate = col >> 9, j = col & 511;
  const int lane = threadIdx.x;
  const float* W = (gate == 0) ? Wf : (gate == 1) ? Wi : (gate == 2) ? Wc : Wo;

  float v[8];
  float m = 0.f;
  #pragma unroll
  for (int e = 0; e < 8; ++e) {
    v[e] = W[(long)(lane * 8 + e) * 512 + j];
    m = fmaxf(m, fabsf(v[e]));
  }
  #pragma unroll
  for (int off = 32; off >= 1; off >>= 1) m = fmaxf(m, __shfl_xor(m, off));
  m = fmaxf(m, 1e-20f);
  if (lane == 0) sW[col] = m;
  const float inv = 127.f / m;
  const int Jc = col >> 4, cl = col & 15;
  #pragma unroll
  for (int e = 0; e < 8; ++e) {
    int k = lane * 8 + e;
    int kk = k >> 6, lp = ((k >> 4) & 3) * 16 + cl, ep = k & 15;
    float qf = rintf(v[e] * inv);
    qf = fminf(fmaxf(qf, -127.f), 127.f);
    Wq[((long)(Jc * 8 + kk) * 64 + lp) * 16 + ep] = (signed char)(int)qf;
  }
}

// ---------------------------------------------------------------------------
// ZX precompute (PROVEN in R12): zxp[mt][Jc][lane] = uint2 of 4 fp16
// C-fragment values (bias + X @ W_x). mt = 4t + batch-group.
// ---------------------------------------------------------------------------
__global__ __launch_bounds__(512) void zx_pre(
    const float* __restrict__ x,
    const float* __restrict__ bf_, const float* __restrict__ bi_,
    const float* __restrict__ bc_, const float* __restrict__ bo_,
    const unsigned short* __restrict__ Wp,
    unsigned int* __restrict__ zxp)
{
  const int tid  = threadIdx.x;
  const int wv   = tid >> 6;
  const int lane = tid & 63;
  const int lrow = lane & 15;
  const int lkg  = lane >> 4;
  const long mt  = (long)blockIdx.x * 2 + (wv & 1);   // 0..4095
  const int  ng  = wv >> 1;                           // 0..3
  const int  t   = (int)(mt >> 2);
  const int  b   = ((int)mt & 3) * 16 + lrow;

  const float* xp = x + ((long)b * T_ + t) * D_ + lkg * 8;
  bf16x8 af[16];
  #pragma unroll
  for (int kk = 0; kk < 16; ++kk) {
    float4 a  = *(const float4*)(xp + kk * 32);
    float4 b4 = *(const float4*)(xp + kk * 32 + 4);
    bf16x8 v;
    v[0]=f2bfs(a.x); v[1]=f2bfs(a.y); v[2]=f2bfs(a.z); v[3]=f2bfs(a.w);
    v[4]=f2bfs(b4.x); v[5]=f2bfs(b4.y); v[6]=f2bfs(b4.z); v[7]=f2bfs(b4.w);
    af[kk] = v;
  }

  f32x4 acc[32];
  #pragma unroll
  for (int nt = 0; nt < 32; ++nt) {
    int col = (ng * 32 + nt) * 16 + lrow;
    const float* bp = col < 512 ? bf_ : col < 1024 ? bi_ : col < 1536 ? bc_ : bo_;
    float bb = bp[col & 511];
    acc[nt] = {bb, bb, bb, bb};
  }

  #pragma unroll
  for (int kk = 0; kk < 16; ++kk) {
    #pragma unroll
    for (int nt = 0; nt < 32; ++nt) {
      int Jc = ng * 32 + nt;
      bf16x8 wf = *(const bf16x8*)(Wp + ((long)(Jc * 32 + kk + 16) * 64 + lane) * 8);
      acc[nt] = __builtin_amdgcn_mfma_f32_16x16x32_bf16(af[kk], wf, acc[nt], 0, 0, 0);
    }
  }

  #pragma unroll
  for (int nt = 0; nt < 32; ++nt) {
    int Jc = ng * 32 + nt;
    unsigned u0 = (unsigned)f2h(acc[nt][0]) | ((unsigned)f2h(acc[nt][1]) << 16);
    unsigned u1 = (unsigned)f2h(acc[nt][2]) | ((unsigned)f2h(acc[nt][3]) << 16);
    uint2 uu; uu.x = u0; uu.y = u1;
    *(uint2*)(zxp + ((mt * 128 + Jc) * 64 + lane) * 2) = uu;
  }
}

// ---------------------------------------------------------------------------
// i8 batch-split recurrence: 32 blocks x 512 threads, ZERO inter-block
// communication. Block bk owns batch rows {2bk, 2bk+1} end-to-end.
// h kept as hi/lo i8 pair in LDS (reconstruction err 3e-5); c in registers;
// weights per-column-scaled i8 streamed from L2 (1 MB/step/CU — the BW
// floor), each tile reused for the hi and lo MFMA. Exact i32 accumulation.
// A rows alternate h-row 0/1, so ALL lanes compute identical gate values
// (no divergence); only lkg==0 lanes store.
// ---------------------------------------------------------------------------
__global__ __launch_bounds__(512, 1) void lstm_i8(
    const float* __restrict__ hinit, const float* __restrict__ cinit,
    const signed char* __restrict__ Wq, const float* __restrict__ sW,
    const unsigned int* __restrict__ zxp,
    unsigned short* __restrict__ hs,   // (T,B,H) bf16
    float* __restrict__ tail)          // h_fin then c_fin
{
  __shared__ __align__(16) signed char hq[2][512];
  __shared__ __align__(16) signed char hr[2][512];

  const int bk   = blockIdx.x;       // 0..31
  const int tid  = threadIdx.x;
  const int wv   = tid >> 6;         // 0..7
  const int lane = tid & 63;
  const int lrow = lane & 15;
  const int lkg  = lane >> 4;
  const int r0   = 2 * bk;           // global batch rows r0, r0+1
  const int g0   = bk >> 3;          // zx batch group
  const int lane_p = ((bk & 7) >> 1) * 16 + lrow;
  const int zoff   = bk & 1;

  // ---- init h (quantize) + c ----
  for (int q = tid; q < 1024; q += 512) {
    int rr = q >> 9, cl = q & 511;
    float h = hinit[(long)(r0 + rr) * 512 + cl];
    float s = h * 127.f;
    float qh = fminf(fmaxf(rintf(s), -127.f), 127.f);
    float qr = fminf(fmaxf(rintf((s - qh) * 127.f), -127.f), 127.f);
    hq[rr][cl] = (signed char)(int)qh;
    hr[rr][cl] = (signed char)(int)qr;
  }
  float cst[4][2];
  #pragma unroll
  for (int tt = 0; tt < 4; ++tt)
    #pragma unroll
    for (int rr = 0; rr < 2; ++rr)
      cst[tt][rr] = cinit[(long)(r0 + rr) * 512 + wv * 64 + tt * 16 + lrow];

  // per-lane combined scale for the 16 tiles: sW[col] / (127*127)
  float swv[16];
  #pragma unroll
  for (int j = 0; j < 16; ++j) {
    int Jc = (j >> 2) * 32 + wv * 4 + (j & 3);
    swv[j] = sW[Jc * 16 + lrow] * (1.f / 16129.f);
  }

  // zx for t=0
  unsigned zxw[16];
  #pragma unroll
  for (int j = 0; j < 16; ++j) {
    int Jc = (j >> 2) * 32 + wv * 4 + (j & 3);
    zxw[j] = zxp[(((long)g0 * 128 + Jc) * 64 + lane_p) * 2 + zoff];
  }
  __syncthreads();

  #pragma unroll 1
  for (int t = 0; t < T_; ++t) {
    // ---- A-frags from LDS (rows alternate 0/1 -> uniform gates) ----
    const int arow = lrow & 1;
    i32x4 ahi[8], alo[8];
    #pragma unroll
    for (int kk = 0; kk < 8; ++kk) {
      ahi[kk] = *(const i32x4*)&hq[arow][kk * 64 + lkg * 16];
      alo[kk] = *(const i32x4*)&hr[arow][kk * 64 + lkg * 16];
    }
    // ---- zx prefetch for t+1 ----
    unsigned zxn[16];
    {
      const long mtn = 4L * ((t + 1 < T_) ? (t + 1) : t) + g0;
      #pragma unroll
      for (int j = 0; j < 16; ++j) {
        int Jc = (j >> 2) * 32 + wv * 4 + (j & 3);
        zxn[j] = zxp[((mtn * 128 + Jc) * 64 + lane_p) * 2 + zoff];
      }
    }
    __syncthreads();   // all LDS reads done before this step's writes

    // ---- 16 tiles x K=512: stream i8 weights, hi+lo MFMA per tile ----
    float z[16][2];
    i32x4 b0[8], b1[8];
    {
      const i32x4* p = (const i32x4*)Wq + (long)((wv * 4) * 8) * 64 + lane;
      #pragma unroll
      for (int kk = 0; kk < 8; ++kk) b0[kk] = p[kk * 64];
    }
    #pragma unroll
    for (int j = 0; j < 16; ++j) {
      if (j + 1 < 16) {
        int jn = j + 1;
        int Jcn = (jn >> 2) * 32 + wv * 4 + (jn & 3);
        const i32x4* p = (const i32x4*)Wq + (long)(Jcn * 8) * 64 + lane;
        if (j & 1) {
          #pragma unroll
          for (int kk = 0; kk < 8; ++kk) b0[kk] = p[kk * 64];
        } else {
          #pragma unroll
          for (int kk = 0; kk < 8; ++kk) b1[kk] = p[kk * 64];
        }
      }
      i32x4 ah = {0, 0, 0, 0}, al = {0, 0, 0, 0};
      if (j & 1) {
        #pragma unroll
        for (int kk = 0; kk < 8; ++kk) {
          ah = __builtin_amdgcn_mfma_i32_16x16x64_i8(ahi[kk], b1[kk], ah, 0, 0, 0);
          al = __builtin_amdgcn_mfma_i32_16x16x64_i8(alo[kk], b1[kk], al, 0, 0, 0);
        }
      } else {
        #pragma unroll
        for (int kk = 0; kk < 8; ++kk) {
          ah = __builtin_amdgcn_mfma_i32_16x16x64_i8(ahi[kk], b0[kk], ah, 0, 0, 0);
          al = __builtin_amdgcn_mfma_i32_16x16x64_i8(alo[kk], b0[kk], al, 0, 0, 0);
        }
      }
      z[j][0] = ((float)ah[0] + (float)al[0] * (1.f / 127.f)) * swv[j];
      z[j][1] = ((float)ah[1] + (float)al[1] * (1.f / 127.f)) * swv[j];
    }

    // ---- gates (uniform across lanes); stores by lkg==0 only ----
    #pragma unroll
    for (int tt = 0; tt < 4; ++tt) {
      #pragma unroll
      for (int rr = 0; rr < 2; ++rr) {
        float zf = z[tt][rr]      + h2f((unsigned short)(rr ? (zxw[tt]      >> 16) : (zxw[tt]      & 0xffffu)));
        float zi = z[4 + tt][rr]  + h2f((unsigned short)(rr ? (zxw[4 + tt]  >> 16) : (zxw[4 + tt]  & 0xffffu)));
        float zg = z[8 + tt][rr]  + h2f((unsigned short)(rr ? (zxw[8 + tt]  >> 16) : (zxw[8 + tt]  & 0xffffu)));
        float zo = z[12 + tt][rr] + h2f((unsigned short)(rr ? (zxw[12 + tt] >> 16) : (zxw[12 + tt] & 0xffffu)));
        float c = sigmoid_f(zf) * cst[tt][rr] + sigmoid_f(zi) * tanh_f(zg);
        cst[tt][rr] = c;
        float hv = sigmoid_f(zo) * tanh_f(c);
        if (lkg == 0) {
          int col = wv * 64 + tt * 16 + lrow;
          float s = hv * 127.f;
          float qh = rintf(s);
          float qr = fminf(fmaxf(rintf((s - qh) * 127.f), -127.f), 127.f);
          hq[rr][col] = (signed char)(int)qh;
          hr[rr][col] = (signed char)(int)qr;
          __builtin_nontemporal_store((unsigned short)f2bfs(hv),
              hs + ((long)t * 64 + r0 + rr) * 512 + col);
          if (t == T_ - 1) {
            tail[(long)(r0 + rr) * 512 + col] = hv;
            tail[64L * 512 + (long)(r0 + rr) * 512 + col] = c;
          }
        }
      }
    }
    __syncthreads();   // h_t visible for next step's A-build
    #pragma unroll
    for (int j = 0; j < 16; ++j) zxw[j] = zxn[j];
  }
}

// ---------------------------------------------------------------------------
// FALLBACK (proven R10): x -> bf16 conversion + one kernel per timestep.
// ---------------------------------------------------------------------------
__global__ __launch_bounds__(256) void xconv(
    const float* __restrict__ x, unsigned short* __restrict__ xb)
{
  long i = ((long)blockIdx.x * 256 + threadIdx.x) * 8;
  float4 a = *(const float4*)(x + i);
  float4 b = *(const float4*)(x + i + 4);
  bf16x8 v;
  v[0] = f2bfs(a.x); v[1] = f2bfs(a.y); v[2] = f2bfs(a.z); v[3] = f2bfs(a.w);
  v[4] = f2bfs(b.x); v[5] = f2bfs(b.y); v[6] = f2bfs(b.z); v[7] = f2bfs(b.w);
  *(bf16x8*)(xb + i) = v;
}

template<bool X16>
__global__ __launch_bounds__(256) void lstm_step(
    const void* __restrict__ xv,
    const float* __restrict__ bf_, const float* __restrict__ bi_,
    const float* __restrict__ bc_, const float* __restrict__ bo_,
    const unsigned short* __restrict__ Wp,
    const unsigned short* __restrict__ hin,
    unsigned short* __restrict__ hout,
    float* __restrict__ cbuf,
    unsigned short* __restrict__ hs,
    float* __restrict__ tail,
    int t)
{
  const int jb   = blockIdx.x;
  const int tid  = threadIdx.x;
  const int wv   = tid >> 6;
  const int lane = tid & 63;
  const int lrow = lane & 15;
  const int lkg  = lane >> 4;
  const int b_arow = wv * 16 + lrow;
  const int jcol   = jb * 16 + lrow;
  const int b_cd0  = wv * 16 + lkg * 4;

  const unsigned short* hrow = hin + (long)b_arow * H_ + lkg * 8;
  bf16x8 hf[16];
  #pragma unroll
  for (int kk = 0; kk < 16; ++kk) hf[kk] = *(const bf16x8*)(hrow + kk * 32);

  bf16x8 xf[16];
  float4 xr[32];
  if constexpr (X16) {
    const unsigned short* xt = (const unsigned short*)xv
        + (long)b_arow * T_ * D_ + (long)t * D_ + lkg * 8;
    #pragma unroll
    for (int kk = 0; kk < 16; ++kk) xf[kk] = *(const bf16x8*)(xt + kk * 32);
  } else {
    const float* xt = (const float*)xv
        + (long)b_arow * T_ * D_ + (long)t * D_ + lkg * 8;
    #pragma unroll
    for (int kk = 0; kk < 16; ++kk) {
      xr[2*kk]   = *(const float4*)(xt + kk * 32);
      xr[2*kk+1] = *(const float4*)(xt + kk * 32 + 4);
    }
  }

  const float vbf = bf_[jcol], vbi = bi_[jcol], vbc = bc_[jcol], vbo = bo_[jcol];
  float c0 = cbuf[(long)(b_cd0 + 0) * H_ + jcol];
  float c1 = cbuf[(long)(b_cd0 + 1) * H_ + jcol];
  float c2 = cbuf[(long)(b_cd0 + 2) * H_ + jcol];
  float c3 = cbuf[(long)(b_cd0 + 3) * H_ + jcol];

  const unsigned short* w0 = Wp + (long)(0 * 32 + jb) * 32 * 512 + lane * 8;
  const unsigned short* w1 = Wp + (long)(1 * 32 + jb) * 32 * 512 + lane * 8;
  const unsigned short* w2 = Wp + (long)(2 * 32 + jb) * 32 * 512 + lane * 8;
  const unsigned short* w3 = Wp + (long)(3 * 32 + jb) * 32 * 512 + lane * 8;

  f32x4 af = {vbf, vbf, vbf, vbf};
  f32x4 ai = {vbi, vbi, vbi, vbi};
  f32x4 ac = {vbc, vbc, vbc, vbc};
  f32x4 ao = {vbo, vbo, vbo, vbo};

  #pragma unroll
  for (int kk = 0; kk < 16; ++kk) {
    bf16x8 ah = hf[kk];
    af = __builtin_amdgcn_mfma_f32_16x16x32_bf16(ah, *(const bf16x8*)(w0 + kk * 512), af, 0, 0, 0);
    ai = __builtin_amdgcn_mfma_f32_16x16x32_bf16(ah, *(const bf16x8*)(w1 + kk * 512), ai, 0, 0, 0);
    ac = __builtin_amdgcn_mfma_f32_16x16x32_bf16(ah, *(const bf16x8*)(w2 + kk * 512), ac, 0, 0, 0);
    ao = __builtin_amdgcn_mfma_f32_16x16x32_bf16(ah, *(const bf16x8*)(w3 + kk * 512), ao, 0, 0, 0);
    bf16x8 ax;
    if constexpr (X16) {
      ax = xf[kk];
    } else {
      float4 xa = xr[2*kk], xb2 = xr[2*kk+1];
      ax[0]=f2bfs(xa.x); ax[1]=f2bfs(xa.y); ax[2]=f2bfs(xa.z); ax[3]=f2bfs(xa.w);
      ax[4]=f2bfs(xb2.x); ax[5]=f2bfs(xb2.y); ax[6]=f2bfs(xb2.z); ax[7]=f2bfs(xb2.w);
    }
    const int k2 = kk + 16;
    af = __builtin_amdgcn_mfma_f32_16x16x32_bf16(ax, *(const bf16x8*)(w0 + k2 * 512), af, 0, 0, 0);
    ai = __builtin_amdgcn_mfma_f32_16x16x32_bf16(ax, *(const bf16x8*)(w1 + k2 * 512), ai, 0, 0, 0);
    ac = __builtin_amdgcn_mfma_f32_16x16x32_bf16(ax, *(const bf16x8*)(w2 + k2 * 512), ac, 0, 0, 0);
    ao = __builtin_amdgcn_mfma_f32_16x16x32_bf16(ax, *(const bf16x8*)(w3 + k2 * 512), ao, 0, 0, 0);
  }

  #pragma unroll
  for (int i2 = 0; i2 < 4; ++i2) {
    float fg = sigmoid_f(af[i2]);
    float ig = sigmoid_f(ai[i2]);
    float gg = tanh_f(ac[i2]);
    float og = sigmoid_f(ao[i2]);
    float cN = (i2 == 0) ? c0 : (i2 == 1) ? c1 : (i2 == 2) ? c2 : c3;
    cN = fg * cN + ig * gg;
    float hv = og * tanh_f(cN);
    if (i2 == 0) c0 = cN; else if (i2 == 1) c1 = cN; else if (i2 == 2) c2 = cN; else c3 = cN;
    unsigned short hb = (unsigned short)f2bfs(hv);
    int brow = b_cd0 + i2;
    cbuf[(long)brow * H_ + jcol] = cN;
    hout[(long)brow * H_ + jcol] = hb;
    __builtin_nontemporal_store(hb, hs + ((long)t * B_ + brow) * H_ + jcol);
    if (t == T_ - 1) {
      tail[(long)brow * H_ + jcol] = hv;
      tail[(long)B_ * H_ + (long)brow * H_ + jcol] = cN;
    }
  }
}

// ---------------------------------------------------------------------------
// Output projection: out(B,T,O) = hs(T,B,H) @ W_hy + b_hy.  (proven)
// ---------------------------------------------------------------------------
__global__ __launch_bounds__(512) void out_proj(
    const unsigned short* __restrict__ hs,
    const unsigned short* __restrict__ Whyp,
    const float* __restrict__ bhy,
    float* __restrict__ out)
{
  const int tid  = threadIdx.x;
  const int wv   = tid >> 6;
  const int lane = tid & 63;
  const int lrow = lane & 15;
  const int lkg  = lane >> 4;
  const int mg = wv >> 2;
  const int ng = wv & 3;
  const long mbase = (long)blockIdx.x * 128 + mg * 64;

  f32x4 acc[4][8];
  #pragma unroll
  for (int mt = 0; mt < 4; ++mt)
    #pragma unroll
    for (int nt = 0; nt < 8; ++nt) {
      float b = bhy[ng * 128 + nt * 16 + lrow];
      acc[mt][nt] = {b, b, b, b};
    }

  const unsigned short* arow = hs + (mbase + lrow) * 512 + lkg * 8;
  const unsigned short* bbas = Whyp + (long)(ng * 8) * 8192 + lane * 8;

  #pragma unroll
  for (int kk = 0; kk < 16; ++kk) {
    bf16x8 a0 = *(const bf16x8*)(arow + 0 * 8192 + kk * 32);
    bf16x8 a1 = *(const bf16x8*)(arow + 1 * 8192 + kk * 32);
    bf16x8 a2 = *(const bf16x8*)(arow + 2 * 8192 + kk * 32);
    bf16x8 a3 = *(const bf16x8*)(arow + 3 * 8192 + kk * 32);
    #pragma unroll
    for (int nt = 0; nt < 8; ++nt) {
      bf16x8 bv = *(const bf16x8*)(bbas + nt * 8192 + kk * 512);
      acc[0][nt] = __builtin_amdgcn_mfma_f32_16x16x32_bf16(a0, bv, acc[0][nt], 0, 0, 0);
      acc[1][nt] = __builtin_amdgcn_mfma_f32_16x16x32_bf16(a1, bv, acc[1][nt], 0, 0, 0);
      acc[2][nt] = __builtin_amdgcn_mfma_f32_16x16x32_bf16(a2, bv, acc[2][nt], 0, 0, 0);
      acc[3][nt] = __builtin_amdgcn_mfma_f32_16x16x32_bf16(a3, bv, acc[3][nt], 0, 0, 0);
    }
  }

  #pragma unroll
  for (int mt = 0; mt < 4; ++mt) {
    #pragma unroll
    for (int i2 = 0; i2 < 4; ++i2) {
      long m = mbase + mt * 16 + lkg * 4 + i2;
      long t = m >> 6, b = m & 63;
      float* orow = out + (b * 1024 + t) * 512;
      #pragma unroll
      for (int nt = 0; nt < 8; ++nt)
        orow[ng * 128 + nt * 16 + lrow] = acc[mt][nt][i2];
    }
  }
}

// ---------------------------------------------------------------------------
extern "C" void kernel_launch(void* const* d_in, const int* in_sizes, int n_in,
                              void* d_out, int out_size, void* d_ws, size_t ws_size,
                              hipStream_t stream) {
  const float* x      = (const float*)d_in[0];
  const float* h_init = (const float*)d_in[1];
  const float* c_init = (const float*)d_in[2];
  const float* W_f = (const float*)d_in[3];
  const float* b_f = (const float*)d_in[4];
  const float* W_i = (const float*)d_in[5];
  const float* b_i = (const float*)d_in[6];
  const float* W_c = (const float*)d_in[7];
  const float* b_c = (const float*)d_in[8];
  const float* W_o = (const float*)d_in[9];
  const float* b_o = (const float*)d_in[10];
  const float* W_hy = (const float*)d_in[11];
  const float* b_hy = (const float*)d_in[12];
  float* out = (float*)d_out;

  // ws layout (bytes)
  const size_t WP_OFF   = 0;                          // 4 MB
  const size_t WHYP_OFF = 4u << 20;                   // 512 KB
  const size_t HBF0_OFF = WHYP_OFF + (512u << 10);    // 64 KB (fallback)
  const size_t HBF1_OFF = HBF0_OFF + (64u << 10);     // 64 KB (fallback)
  const size_t CB_OFF   = HBF1_OFF + (64u << 10);     // 128 KB fp32 c (fallback)
  const size_t WQ_OFF   = CB_OFF + (128u << 10);      // 1 MB i8 weights
  const size_t SW_OFF   = WQ_OFF + (1u << 20);        // 8 KB scales
  const size_t HS_OFF   = 8u << 20;                   // 64 MB hs
  const size_t HS_BYTES = (size_t)T_ * B_ * H_ * 2;
  const size_t ZX_OFF   = HS_OFF + HS_BYTES;          // 256 MB fp16 (new path)
  const size_t ZX_BYTES = (size_t)4096 * 128 * 512;
  const size_t XB_OFF   = ZX_OFF;                     // fallback-big: 64 MB bf16 x
  const size_t XB_BYTES = (size_t)B_ * T_ * D_ * 2;
  const size_t NEED_MIN = HS_OFF + HS_BYTES;          // 72 MB
  const size_t NEED_NEW = ZX_OFF + ZX_BYTES;          // 328 MB
  const size_t NEED_FBB = XB_OFF + XB_BYTES;          // 136 MB
  if (ws_size < NEED_MIN) return;
  const bool newpath = (ws_size >= NEED_NEW);
  const bool fb_big  = (!newpath) && (ws_size >= NEED_FBB);

  unsigned char* w = (unsigned char*)d_ws;
  unsigned short* Wp   = (unsigned short*)(w + WP_OFF);
  unsigned short* Whyp = (unsigned short*)(w + WHYP_OFF);
  unsigned short* hbf0 = (unsigned short*)(w + HBF0_OFF);
  unsigned short* hbf1 = (unsigned short*)(w + HBF1_OFF);
  float*          cbuf = (float*)(w + CB_OFF);
  signed char*    Wq   = (signed char*)(w + WQ_OFF);
  float*          sW   = (float*)(w + SW_OFF);
  unsigned short* hs   = (unsigned short*)(w + HS_OFF);
  unsigned int*   zxp  = (unsigned int*)(w + ZX_OFF);
  unsigned short* xb   = (unsigned short*)(w + XB_OFF);

  // 1) pack weights + fallback state staging
  const long total = 1024L * 2048 + 512L * 512 + 64L * 512 + 64L * 512;
  int pgrid = (int)((total + 255) / 256);
  pack_setup<<<pgrid, 256, 0, stream>>>(W_f, W_i, W_c, W_o, W_hy, h_init, c_init,
                                        Wp, Whyp, hbf0, cbuf);

  float* tail = out + (size_t)B_ * T_ * O_;

  if (newpath) {
    // 2) quantize h-part weights to per-column-scaled i8
    wquant<<<2048, 64, 0, stream>>>(W_f, W_i, W_c, W_o, Wq, sW);
    // 3) ZX = bias + X @ W_x (fp16, C-frag layout) — proven in R12
    zx_pre<<<2048, 512, 0, stream>>>(x, b_f, b_i, b_c, b_o, Wp, zxp);
    // 4) zero-communication i8 recurrence: 32 blocks, 2 batch rows each
    lstm_i8<<<32, 512, 0, stream>>>(h_init, c_init, Wq, sW, zxp, hs, tail);
  } else {
    // fallback: proven kernel-per-timestep chain (R10)
    if (fb_big) {
      const long nx = (long)B_ * T_ * D_;
      int xgrid = (int)(nx / (256 * 8));
      xconv<<<xgrid, 256, 0, stream>>>(x, xb);
    }
    for (int t = 0; t < T_; ++t) {
      const unsigned short* hin  = (t & 1) ? hbf1 : hbf0;
      unsigned short*       hout = (t & 1) ? hbf0 : hbf1;
      if (fb_big) {
        lstm_step<true><<<NBLK, 256, 0, stream>>>(
            xb, b_f, b_i, b_c, b_o, Wp, hin, hout, cbuf, hs, tail, t);
      } else {
        lstm_step<false><<<NBLK, 256, 0, stream>>>(
            x, b_f, b_i, b_c, b_o, Wp, hin, hout, cbuf, hs, tail, t);
      }
    }
  }

  // 5) output projection
  out_proj<<<512, 512, 0, stream>>>(hs, Whyp, b_hy, out);
}

// Round 14
// 7741.645 us; speedup vs baseline: 7.4930x; 5.3098x over previous
//
#include <hip/hip_runtime.h>
#include <hip/hip_bf16.h>
#include <hip/hip_fp16.h>

#define B_ 64
#define T_ 1024
#define D_ 512
#define H_ 512
#define O_ 512
#define NBLK 32   // step-kernel blocks

using bf16x8 = __attribute__((ext_vector_type(8))) short;
using f32x4  = __attribute__((ext_vector_type(4))) float;

__device__ __forceinline__ short f2bfs(float f) {
  return (short)__builtin_bit_cast(unsigned short, __float2bfloat16(f));
}
__device__ __forceinline__ float sigmoid_f(float v) {
  return 1.0f / (1.0f + __expf(-v));
}
__device__ __forceinline__ float tanh_f(float v) {
  float a = fabsf(v);
  float e = __expf(-2.0f * a);
  float t = (1.0f - e) / (1.0f + e);
  return copysignf(t, v);
}
__device__ __forceinline__ unsigned short f2h(float f) {
  return __half_as_ushort(__float2half_rn(f));
}
__device__ __forceinline__ float h2f(unsigned short u) {
  __half_raw r; r.x = u; return __half2float(__half(r));
}

// ---------------------------------------------------------------------------
// Setup: pack W_all (1024x2048) and W_hy (512x512) into MFMA B-fragment order
// (bf16); stage h_init (bf16) + c_init (fp32).
// ---------------------------------------------------------------------------
__global__ __launch_bounds__(256) void pack_setup(
    const float* __restrict__ Wf, const float* __restrict__ Wi,
    const float* __restrict__ Wc, const float* __restrict__ Wo,
    const float* __restrict__ Why, const float* __restrict__ hinit,
    const float* __restrict__ cinit,
    unsigned short* __restrict__ Wp, unsigned short* __restrict__ Whyp,
    unsigned short* __restrict__ hbf0, float* __restrict__ cbuf)
{
  long idx = (long)blockIdx.x * blockDim.x + threadIdx.x;
  const long NW = 1024L * 2048;
  const long NY = 512L * 512;
  const long NH = 64L * 512;
  const long NC = 64L * 512;
  if (idx < NW) {
    int e = idx & 7, l = (idx >> 3) & 63, kk = (idx >> 9) & 31;
    int Jc = (int)(idx >> 14);                   // 0..127
    int k = kk * 32 + (l >> 4) * 8 + e;          // 0..1023
    int col = Jc * 16 + (l & 15);                // 0..2047
    int gg = col >> 9, j = col & 511;
    const float* W = (gg == 0) ? Wf : (gg == 1) ? Wi : (gg == 2) ? Wc : Wo;
    Wp[idx] = (unsigned short)f2bfs(W[(long)k * 512 + j]);
  } else if (idx < NW + NY) {
    long q = idx - NW;
    int e = q & 7, l = (q >> 3) & 63, kk = (q >> 9) & 15;
    int J = (int)(q >> 13);
    int k = kk * 32 + (l >> 4) * 8 + e;
    int col = J * 16 + (l & 15);
    Whyp[q] = (unsigned short)f2bfs(Why[(long)k * 512 + col]);
  } else if (idx < NW + NY + NH) {
    long q = idx - NW - NY;
    hbf0[q] = (unsigned short)f2bfs(hinit[q]);
  } else if (idx < NW + NY + NH + NC) {
    long q = idx - NW - NY - NH;
    cbuf[q] = cinit[q];
  }
}

// ---------------------------------------------------------------------------
// ZX precompute (PROVEN R12/R13): zxp[mt][Jc][lane] = uint2 of 4 fp16
// C-fragment values (bias + X @ W_x). mt = 4t + batch-group (16 rows).
// ---------------------------------------------------------------------------
__global__ __launch_bounds__(512) void zx_pre(
    const float* __restrict__ x,
    const float* __restrict__ bf_, const float* __restrict__ bi_,
    const float* __restrict__ bc_, const float* __restrict__ bo_,
    const unsigned short* __restrict__ Wp,
    unsigned int* __restrict__ zxp)
{
  const int tid  = threadIdx.x;
  const int wv   = tid >> 6;
  const int lane = tid & 63;
  const int lrow = lane & 15;
  const int lkg  = lane >> 4;
  const long mt  = (long)blockIdx.x * 2 + (wv & 1);   // 0..4095
  const int  ng  = wv >> 1;                           // 0..3
  const int  t   = (int)(mt >> 2);
  const int  b   = ((int)mt & 3) * 16 + lrow;

  const float* xp = x + ((long)b * T_ + t) * D_ + lkg * 8;
  bf16x8 af[16];
  #pragma unroll
  for (int kk = 0; kk < 16; ++kk) {
    float4 a  = *(const float4*)(xp + kk * 32);
    float4 b4 = *(const float4*)(xp + kk * 32 + 4);
    bf16x8 v;
    v[0]=f2bfs(a.x); v[1]=f2bfs(a.y); v[2]=f2bfs(a.z); v[3]=f2bfs(a.w);
    v[4]=f2bfs(b4.x); v[5]=f2bfs(b4.y); v[6]=f2bfs(b4.z); v[7]=f2bfs(b4.w);
    af[kk] = v;
  }

  f32x4 acc[32];
  #pragma unroll
  for (int nt = 0; nt < 32; ++nt) {
    int col = (ng * 32 + nt) * 16 + lrow;
    const float* bp = col < 512 ? bf_ : col < 1024 ? bi_ : col < 1536 ? bc_ : bo_;
    float bb = bp[col & 511];
    acc[nt] = {bb, bb, bb, bb};
  }

  #pragma unroll
  for (int kk = 0; kk < 16; ++kk) {
    #pragma unroll
    for (int nt = 0; nt < 32; ++nt) {
      int Jc = ng * 32 + nt;
      bf16x8 wf = *(const bf16x8*)(Wp + ((long)(Jc * 32 + kk + 16) * 64 + lane) * 8);
      acc[nt] = __builtin_amdgcn_mfma_f32_16x16x32_bf16(af[kk], wf, acc[nt], 0, 0, 0);
    }
  }

  #pragma unroll
  for (int nt = 0; nt < 32; ++nt) {
    int Jc = ng * 32 + nt;
    unsigned u0 = (unsigned)f2h(acc[nt][0]) | ((unsigned)f2h(acc[nt][1]) << 16);
    unsigned u1 = (unsigned)f2h(acc[nt][2]) | ((unsigned)f2h(acc[nt][3]) << 16);
    uint2 uu; uu.x = u0; uu.y = u1;
    *(uint2*)(zxp + ((mt * 128 + Jc) * 64 + lane) * 2) = uu;
  }
}

// ---------------------------------------------------------------------------
// LIGHT step kernel: one timestep, h-GEMM only (K=512); acc init from ZX.
// Kernel boundary = grid barrier + coherence (R10-proven, 10.6 us/node).
// Per block: 64 KB weights, 4 uint2 zx/lane, h A-frags; no x, no biases.
// ---------------------------------------------------------------------------
__global__ __launch_bounds__(256) void lstm_step_zx(
    const unsigned short* __restrict__ Wp,
    const unsigned int* __restrict__ zxp,
    const unsigned short* __restrict__ hin,   // (B,H) bf16  h_{t-1}
    unsigned short* __restrict__ hout,        // (B,H) bf16  h_t
    float* __restrict__ cbuf,                 // (B,H) fp32
    unsigned short* __restrict__ hs,          // (T,B,H) bf16
    float* __restrict__ tail,
    int t)
{
  const int jb   = blockIdx.x;
  const int tid  = threadIdx.x;
  const int wv   = tid >> 6;
  const int lane = tid & 63;
  const int lrow = lane & 15;
  const int lkg  = lane >> 4;
  const int b_arow = wv * 16 + lrow;
  const int jcol   = jb * 16 + lrow;
  const int b_cd0  = wv * 16 + lkg * 4;

  // ---- zx (acc init, fp16 C-frag: bias + x@Wx) ----
  const long mt = 4L * t + wv;
  uint2 zq[4];
  #pragma unroll
  for (int gg = 0; gg < 4; ++gg)
    zq[gg] = *(const uint2*)(zxp + ((mt * 128 + (gg * 32 + jb)) * 64 + lane) * 2);

  // ---- h A-frags ----
  const unsigned short* hrow = hin + (long)b_arow * H_ + lkg * 8;
  bf16x8 hf[16];
  #pragma unroll
  for (int kk = 0; kk < 16; ++kk) hf[kk] = *(const bf16x8*)(hrow + kk * 32);

  // ---- cell state ----
  float c0 = cbuf[(long)(b_cd0 + 0) * H_ + jcol];
  float c1 = cbuf[(long)(b_cd0 + 1) * H_ + jcol];
  float c2 = cbuf[(long)(b_cd0 + 2) * H_ + jcol];
  float c3 = cbuf[(long)(b_cd0 + 3) * H_ + jcol];

  const unsigned short* w0 = Wp + (long)(0 * 32 + jb) * 32 * 512 + lane * 8;
  const unsigned short* w1 = Wp + (long)(1 * 32 + jb) * 32 * 512 + lane * 8;
  const unsigned short* w2 = Wp + (long)(2 * 32 + jb) * 32 * 512 + lane * 8;
  const unsigned short* w3 = Wp + (long)(3 * 32 + jb) * 32 * 512 + lane * 8;

  f32x4 af, ai, ac, ao;
  af[0] = h2f((unsigned short)(zq[0].x & 0xffffu)); af[1] = h2f((unsigned short)(zq[0].x >> 16));
  af[2] = h2f((unsigned short)(zq[0].y & 0xffffu)); af[3] = h2f((unsigned short)(zq[0].y >> 16));
  ai[0] = h2f((unsigned short)(zq[1].x & 0xffffu)); ai[1] = h2f((unsigned short)(zq[1].x >> 16));
  ai[2] = h2f((unsigned short)(zq[1].y & 0xffffu)); ai[3] = h2f((unsigned short)(zq[1].y >> 16));
  ac[0] = h2f((unsigned short)(zq[2].x & 0xffffu)); ac[1] = h2f((unsigned short)(zq[2].x >> 16));
  ac[2] = h2f((unsigned short)(zq[2].y & 0xffffu)); ac[3] = h2f((unsigned short)(zq[2].y >> 16));
  ao[0] = h2f((unsigned short)(zq[3].x & 0xffffu)); ao[1] = h2f((unsigned short)(zq[3].x >> 16));
  ao[2] = h2f((unsigned short)(zq[3].y & 0xffffu)); ao[3] = h2f((unsigned short)(zq[3].y >> 16));

  // ---- h-GEMM: K=512 ----
  #pragma unroll
  for (int kk = 0; kk < 16; ++kk) {
    bf16x8 ah = hf[kk];
    af = __builtin_amdgcn_mfma_f32_16x16x32_bf16(ah, *(const bf16x8*)(w0 + kk * 512), af, 0, 0, 0);
    ai = __builtin_amdgcn_mfma_f32_16x16x32_bf16(ah, *(const bf16x8*)(w1 + kk * 512), ai, 0, 0, 0);
    ac = __builtin_amdgcn_mfma_f32_16x16x32_bf16(ah, *(const bf16x8*)(w2 + kk * 512), ac, 0, 0, 0);
    ao = __builtin_amdgcn_mfma_f32_16x16x32_bf16(ah, *(const bf16x8*)(w3 + kk * 512), ao, 0, 0, 0);
  }

  // ---- gates + state update (C/D: col=lane&15, row=(lane>>4)*4+i) ----
  #pragma unroll
  for (int i2 = 0; i2 < 4; ++i2) {
    float fg = sigmoid_f(af[i2]);
    float ig = sigmoid_f(ai[i2]);
    float gg = tanh_f(ac[i2]);
    float og = sigmoid_f(ao[i2]);
    float cN = (i2 == 0) ? c0 : (i2 == 1) ? c1 : (i2 == 2) ? c2 : c3;
    cN = fg * cN + ig * gg;
    float hv = og * tanh_f(cN);
    if (i2 == 0) c0 = cN; else if (i2 == 1) c1 = cN; else if (i2 == 2) c2 = cN; else c3 = cN;
    unsigned short hb = (unsigned short)f2bfs(hv);
    int brow = b_cd0 + i2;
    cbuf[(long)brow * H_ + jcol] = cN;
    hout[(long)brow * H_ + jcol] = hb;
    __builtin_nontemporal_store(hb, hs + ((long)t * B_ + brow) * H_ + jcol);
    if (t == T_ - 1) {
      tail[(long)brow * H_ + jcol] = hv;
      tail[(long)B_ * H_ + (long)brow * H_ + jcol] = cN;
    }
  }
}

// ---------------------------------------------------------------------------
// FALLBACK (proven R10): x -> bf16 conversion + heavy one-step kernel.
// ---------------------------------------------------------------------------
__global__ __launch_bounds__(256) void xconv(
    const float* __restrict__ x, unsigned short* __restrict__ xb)
{
  long i = ((long)blockIdx.x * 256 + threadIdx.x) * 8;
  float4 a = *(const float4*)(x + i);
  float4 b = *(const float4*)(x + i + 4);
  bf16x8 v;
  v[0] = f2bfs(a.x); v[1] = f2bfs(a.y); v[2] = f2bfs(a.z); v[3] = f2bfs(a.w);
  v[4] = f2bfs(b.x); v[5] = f2bfs(b.y); v[6] = f2bfs(b.z); v[7] = f2bfs(b.w);
  *(bf16x8*)(xb + i) = v;
}

template<bool X16>
__global__ __launch_bounds__(256) void lstm_step(
    const void* __restrict__ xv,
    const float* __restrict__ bf_, const float* __restrict__ bi_,
    const float* __restrict__ bc_, const float* __restrict__ bo_,
    const unsigned short* __restrict__ Wp,
    const unsigned short* __restrict__ hin,
    unsigned short* __restrict__ hout,
    float* __restrict__ cbuf,
    unsigned short* __restrict__ hs,
    float* __restrict__ tail,
    int t)
{
  const int jb   = blockIdx.x;
  const int tid  = threadIdx.x;
  const int wv   = tid >> 6;
  const int lane = tid & 63;
  const int lrow = lane & 15;
  const int lkg  = lane >> 4;
  const int b_arow = wv * 16 + lrow;
  const int jcol   = jb * 16 + lrow;
  const int b_cd0  = wv * 16 + lkg * 4;

  const unsigned short* hrow = hin + (long)b_arow * H_ + lkg * 8;
  bf16x8 hf[16];
  #pragma unroll
  for (int kk = 0; kk < 16; ++kk) hf[kk] = *(const bf16x8*)(hrow + kk * 32);

  bf16x8 xf[16];
  float4 xr[32];
  if constexpr (X16) {
    const unsigned short* xt = (const unsigned short*)xv
        + (long)b_arow * T_ * D_ + (long)t * D_ + lkg * 8;
    #pragma unroll
    for (int kk = 0; kk < 16; ++kk) xf[kk] = *(const bf16x8*)(xt + kk * 32);
  } else {
    const float* xt = (const float*)xv
        + (long)b_arow * T_ * D_ + (long)t * D_ + lkg * 8;
    #pragma unroll
    for (int kk = 0; kk < 16; ++kk) {
      xr[2*kk]   = *(const float4*)(xt + kk * 32);
      xr[2*kk+1] = *(const float4*)(xt + kk * 32 + 4);
    }
  }

  const float vbf = bf_[jcol], vbi = bi_[jcol], vbc = bc_[jcol], vbo = bo_[jcol];
  float c0 = cbuf[(long)(b_cd0 + 0) * H_ + jcol];
  float c1 = cbuf[(long)(b_cd0 + 1) * H_ + jcol];
  float c2 = cbuf[(long)(b_cd0 + 2) * H_ + jcol];
  float c3 = cbuf[(long)(b_cd0 + 3) * H_ + jcol];

  const unsigned short* w0 = Wp + (long)(0 * 32 + jb) * 32 * 512 + lane * 8;
  const unsigned short* w1 = Wp + (long)(1 * 32 + jb) * 32 * 512 + lane * 8;
  const unsigned short* w2 = Wp + (long)(2 * 32 + jb) * 32 * 512 + lane * 8;
  const unsigned short* w3 = Wp + (long)(3 * 32 + jb) * 32 * 512 + lane * 8;

  f32x4 af = {vbf, vbf, vbf, vbf};
  f32x4 ai = {vbi, vbi, vbi, vbi};
  f32x4 ac = {vbc, vbc, vbc, vbc};
  f32x4 ao = {vbo, vbo, vbo, vbo};

  #pragma unroll
  for (int kk = 0; kk < 16; ++kk) {
    bf16x8 ah = hf[kk];
    af = __builtin_amdgcn_mfma_f32_16x16x32_bf16(ah, *(const bf16x8*)(w0 + kk * 512), af, 0, 0, 0);
    ai = __builtin_amdgcn_mfma_f32_16x16x32_bf16(ah, *(const bf16x8*)(w1 + kk * 512), ai, 0, 0, 0);
    ac = __builtin_amdgcn_mfma_f32_16x16x32_bf16(ah, *(const bf16x8*)(w2 + kk * 512), ac, 0, 0, 0);
    ao = __builtin_amdgcn_mfma_f32_16x16x32_bf16(ah, *(const bf16x8*)(w3 + kk * 512), ao, 0, 0, 0);
    bf16x8 ax;
    if constexpr (X16) {
      ax = xf[kk];
    } else {
      float4 xa = xr[2*kk], xb2 = xr[2*kk+1];
      ax[0]=f2bfs(xa.x); ax[1]=f2bfs(xa.y); ax[2]=f2bfs(xa.z); ax[3]=f2bfs(xa.w);
      ax[4]=f2bfs(xb2.x); ax[5]=f2bfs(xb2.y); ax[6]=f2bfs(xb2.z); ax[7]=f2bfs(xb2.w);
    }
    const int k2 = kk + 16;
    af = __builtin_amdgcn_mfma_f32_16x16x32_bf16(ax, *(const bf16x8*)(w0 + k2 * 512), af, 0, 0, 0);
    ai = __builtin_amdgcn_mfma_f32_16x16x32_bf16(ax, *(const bf16x8*)(w1 + k2 * 512), ai, 0, 0, 0);
    ac = __builtin_amdgcn_mfma_f32_16x16x32_bf16(ax, *(const bf16x8*)(w2 + k2 * 512), ac, 0, 0, 0);
    ao = __builtin_amdgcn_mfma_f32_16x16x32_bf16(ax, *(const bf16x8*)(w3 + k2 * 512), ao, 0, 0, 0);
  }

  #pragma unroll
  for (int i2 = 0; i2 < 4; ++i2) {
    float fg = sigmoid_f(af[i2]);
    float ig = sigmoid_f(ai[i2]);
    float gg = tanh_f(ac[i2]);
    float og = sigmoid_f(ao[i2]);
    float cN = (i2 == 0) ? c0 : (i2 == 1) ? c1 : (i2 == 2) ? c2 : c3;
    cN = fg * cN + ig * gg;
    float hv = og * tanh_f(cN);
    if (i2 == 0) c0 = cN; else if (i2 == 1) c1 = cN; else if (i2 == 2) c2 = cN; else c3 = cN;
    unsigned short hb = (unsigned short)f2bfs(hv);
    int brow = b_cd0 + i2;
    cbuf[(long)brow * H_ + jcol] = cN;
    hout[(long)brow * H_ + jcol] = hb;
    __builtin_nontemporal_store(hb, hs + ((long)t * B_ + brow) * H_ + jcol);
    if (t == T_ - 1) {
      tail[(long)brow * H_ + jcol] = hv;
      tail[(long)B_ * H_ + (long)brow * H_ + jcol] = cN;
    }
  }
}

// ---------------------------------------------------------------------------
// Output projection: out(B,T,O) = hs(T,B,H) @ W_hy + b_hy.  (proven)
// ---------------------------------------------------------------------------
__global__ __launch_bounds__(512) void out_proj(
    const unsigned short* __restrict__ hs,
    const unsigned short* __restrict__ Whyp,
    const float* __restrict__ bhy,
    float* __restrict__ out)
{
  const int tid  = threadIdx.x;
  const int wv   = tid >> 6;
  const int lane = tid & 63;
  const int lrow = lane & 15;
  const int lkg  = lane >> 4;
  const int mg = wv >> 2;
  const int ng = wv & 3;
  const long mbase = (long)blockIdx.x * 128 + mg * 64;

  f32x4 acc[4][8];
  #pragma unroll
  for (int mt = 0; mt < 4; ++mt)
    #pragma unroll
    for (int nt = 0; nt < 8; ++nt) {
      float b = bhy[ng * 128 + nt * 16 + lrow];
      acc[mt][nt] = {b, b, b, b};
    }

  const unsigned short* arow = hs + (mbase + lrow) * 512 + lkg * 8;
  const unsigned short* bbas = Whyp + (long)(ng * 8) * 8192 + lane * 8;

  #pragma unroll
  for (int kk = 0; kk < 16; ++kk) {
    bf16x8 a0 = *(const bf16x8*)(arow + 0 * 8192 + kk * 32);
    bf16x8 a1 = *(const bf16x8*)(arow + 1 * 8192 + kk * 32);
    bf16x8 a2 = *(const bf16x8*)(arow + 2 * 8192 + kk * 32);
    bf16x8 a3 = *(const bf16x8*)(arow + 3 * 8192 + kk * 32);
    #pragma unroll
    for (int nt = 0; nt < 8; ++nt) {
      bf16x8 bv = *(const bf16x8*)(bbas + nt * 8192 + kk * 512);
      acc[0][nt] = __builtin_amdgcn_mfma_f32_16x16x32_bf16(a0, bv, acc[0][nt], 0, 0, 0);
      acc[1][nt] = __builtin_amdgcn_mfma_f32_16x16x32_bf16(a1, bv, acc[1][nt], 0, 0, 0);
      acc[2][nt] = __builtin_amdgcn_mfma_f32_16x16x32_bf16(a2, bv, acc[2][nt], 0, 0, 0);
      acc[3][nt] = __builtin_amdgcn_mfma_f32_16x16x32_bf16(a3, bv, acc[3][nt], 0, 0, 0);
    }
  }

  #pragma unroll
  for (int mt = 0; mt < 4; ++mt) {
    #pragma unroll
    for (int i2 = 0; i2 < 4; ++i2) {
      long m = mbase + mt * 16 + lkg * 4 + i2;
      long t = m >> 6, b = m & 63;
      float* orow = out + (b * 1024 + t) * 512;
      #pragma unroll
      for (int nt = 0; nt < 8; ++nt)
        orow[ng * 128 + nt * 16 + lrow] = acc[mt][nt][i2];
    }
  }
}

// ---------------------------------------------------------------------------
extern "C" void kernel_launch(void* const* d_in, const int* in_sizes, int n_in,
                              void* d_out, int out_size, void* d_ws, size_t ws_size,
                              hipStream_t stream) {
  const float* x      = (const float*)d_in[0];
  const float* h_init = (const float*)d_in[1];
  const float* c_init = (const float*)d_in[2];
  const float* W_f = (const float*)d_in[3];
  const float* b_f = (const float*)d_in[4];
  const float* W_i = (const float*)d_in[5];
  const float* b_i = (const float*)d_in[6];
  const float* W_c = (const float*)d_in[7];
  const float* b_c = (const float*)d_in[8];
  const float* W_o = (const float*)d_in[9];
  const float* b_o = (const float*)d_in[10];
  const float* W_hy = (const float*)d_in[11];
  const float* b_hy = (const float*)d_in[12];
  float* out = (float*)d_out;

  // ws layout (bytes)
  const size_t WP_OFF   = 0;                          // 4 MB
  const size_t WHYP_OFF = 4u << 20;                   // 512 KB
  const size_t HBF0_OFF = WHYP_OFF + (512u << 10);    // 64 KB
  const size_t HBF1_OFF = HBF0_OFF + (64u << 10);     // 64 KB
  const size_t CB_OFF   = HBF1_OFF + (64u << 10);     // 128 KB fp32 c-state
  const size_t HS_OFF   = 8u << 20;                   // 64 MB hs
  const size_t HS_BYTES = (size_t)T_ * B_ * H_ * 2;
  const size_t ZX_OFF   = HS_OFF + HS_BYTES;          // 256 MB fp16 zx
  const size_t ZX_BYTES = (size_t)4096 * 128 * 512;
  const size_t XB_OFF   = ZX_OFF;                     // fallback-big bf16 x
  const size_t XB_BYTES = (size_t)B_ * T_ * D_ * 2;
  const size_t NEED_MIN = HS_OFF + HS_BYTES;          // 72 MB
  const size_t NEED_NEW = ZX_OFF + ZX_BYTES;          // 328 MB (proven avail.)
  const size_t NEED_FBB = XB_OFF + XB_BYTES;          // 136 MB
  if (ws_size < NEED_MIN) return;
  const bool newpath = (ws_size >= NEED_NEW);
  const bool fb_big  = (!newpath) && (ws_size >= NEED_FBB);

  unsigned char* w = (unsigned char*)d_ws;
  unsigned short* Wp   = (unsigned short*)(w + WP_OFF);
  unsigned short* Whyp = (unsigned short*)(w + WHYP_OFF);
  unsigned short* hbf0 = (unsigned short*)(w + HBF0_OFF);
  unsigned short* hbf1 = (unsigned short*)(w + HBF1_OFF);
  float*          cbuf = (float*)(w + CB_OFF);
  unsigned short* hs   = (unsigned short*)(w + HS_OFF);
  unsigned int*   zxp  = (unsigned int*)(w + ZX_OFF);
  unsigned short* xb   = (unsigned short*)(w + XB_OFF);

  // 1) pack weights + state staging
  const long total = 1024L * 2048 + 512L * 512 + 64L * 512 + 64L * 512;
  int pgrid = (int)((total + 255) / 256);
  pack_setup<<<pgrid, 256, 0, stream>>>(W_f, W_i, W_c, W_o, W_hy, h_init, c_init,
                                        Wp, Whyp, hbf0, cbuf);

  float* tail = out + (size_t)B_ * T_ * O_;

  if (newpath) {
    // 2) ZX = bias + X @ W_x (fp16 C-frag layout) — proven
    zx_pre<<<2048, 512, 0, stream>>>(x, b_f, b_i, b_c, b_o, Wp, zxp);
    // 3) light step kernels: h-GEMM only, K=512, acc init from ZX
    for (int t = 0; t < T_; ++t) {
      const unsigned short* hin  = (t & 1) ? hbf1 : hbf0;
      unsigned short*       hout = (t & 1) ? hbf0 : hbf1;
      lstm_step_zx<<<NBLK, 256, 0, stream>>>(Wp, zxp, hin, hout, cbuf, hs, tail, t);
    }
  } else {
    // fallback: proven R10 heavy step kernels
    if (fb_big) {
      const long nx = (long)B_ * T_ * D_;
      int xgrid = (int)(nx / (256 * 8));
      xconv<<<xgrid, 256, 0, stream>>>(x, xb);
    }
    for (int t = 0; t < T_; ++t) {
      const unsigned short* hin  = (t & 1) ? hbf1 : hbf0;
      unsigned short*       hout = (t & 1) ? hbf0 : hbf1;
      if (fb_big) {
        lstm_step<true><<<NBLK, 256, 0, stream>>>(
            xb, b_f, b_i, b_c, b_o, Wp, hin, hout, cbuf, hs, tail, t);
      } else {
        lstm_step<false><<<NBLK, 256, 0, stream>>>(
            x, b_f, b_i, b_c, b_o, Wp, hin, hout, cbuf, hs, tail, t);
      }
    }
  }

  // 4) output projection
  out_proj<<<512, 512, 0, stream>>>(hs, Whyp, b_hy, out);
}